// Round 7
// baseline (858.697 us; speedup 1.0000x reference)
//
#include <hip/hip_runtime.h>
#include <hip/hip_bf16.h>

// WindowAttention fused kernel v10 (MI355X / gfx950)
// One block = one window. 4 waves, wave = head everywhere.
// v10 goal: 5 waves/EU (20 waves/CU) instead of 4 (16).
//  - LDS 16KB only: X staged bf16 @0 (swz), O aliases X after ph2+3 barrier.
//  - Q,K,V all in registers (pkQ/pkK/pkV, 48 persistent); qb built with the
//    same 8-shuffle redistribution as kb (verified in v5), va as always.
//  - ph1 reads x fragments from LDS per tile (v5 mechanism) -> no 64-reg xa.
//  - bias folded into MFMA C-operand (Q weights pre-scaled by SCALE in prep);
//    mask folded into QK^T C-operand (deletes adds, shortens m4 lives).
//  - amdgpu_waves_per_eu(5): forces <=~102 total regs (incl AGPR).
//  - v9 lesson: VGPR_Count column is arch-VGPRs only; waves_per_eu(4,4) was
//    a no-op because 4/EU was already the operating point.

#define T49  49
#define CDIM 128
#define NW   64
#define SCALEF 0.17677669529663689f   // 1/sqrt(32)

typedef short bf16x8 __attribute__((ext_vector_type(8)));
typedef float f32x4  __attribute__((ext_vector_type(4)));

union B8 { unsigned int u[4]; bf16x8 v; };

__device__ __forceinline__ unsigned int pk2(float a, float b) {
  __hip_bfloat162 h = __float22bfloat162_rn(make_float2(a, b));
  unsigned int u;
  __builtin_memcpy(&u, &h, 4);
  return u;
}

__device__ __forceinline__ unsigned short f2bf(float f) {
  unsigned int u = __builtin_bit_cast(unsigned int, f);
  u += 0x7fffu + ((u >> 16) & 1u);
  return (unsigned short)(u >> 16);
}

// prep: bf16 weights (Q rows pre-scaled by SCALEF) + padded mask
//   maskp[w][q][k] = mask - rowmax(mask)  (q<49,k<49)
//                  = -1e30                (q<49,k>=49)  -> exp()=0 exactly
//                  = 0                    (q>=49)       -> finite garbage, unused
__global__ void prep_kernel(const float* __restrict__ wq, const float* __restrict__ wp,
                            const float* __restrict__ mask,
                            short* __restrict__ wq_bf, short* __restrict__ wp_bf,
                            float* __restrict__ maskp) {
  const int i = blockIdx.x * 256 + threadIdx.x;      // grid covers 262144
  const int w = i >> 12, q = (i >> 6) & 63, k = i & 63;
  // one wave == one (w,q) row, lane == k  (256 % 64 == 0)
  float val = -3.0e38f;
  if (q < T49 && k < T49) val = mask[(w * T49 + q) * T49 + k];
  float rm = val;
  rm = fmaxf(rm, __shfl_xor(rm, 1, 64));
  rm = fmaxf(rm, __shfl_xor(rm, 2, 64));
  rm = fmaxf(rm, __shfl_xor(rm, 4, 64));
  rm = fmaxf(rm, __shfl_xor(rm, 8, 64));
  rm = fmaxf(rm, __shfl_xor(rm, 16, 64));
  rm = fmaxf(rm, __shfl_xor(rm, 32, 64));
  float mv;
  if (q >= T49)      mv = 0.0f;
  else if (k >= T49) mv = -1e30f;
  else               mv = val - rm;
  maskp[i] = mv;
  if (i < 3 * CDIM * CDIM) {
    float wv_ = wq[i];
    if (i < CDIM * CDIM) wv_ *= SCALEF;              // Q rows pre-scaled
    wq_bf[i] = (short)f2bf(wv_);
  }
  if (i < CDIM * CDIM) wp_bf[i] = (short)f2bf(wp[i]);
}

__global__ __launch_bounds__(256)
__attribute__((amdgpu_waves_per_eu(5)))
void winattn_kernel(const float* __restrict__ x, const float* __restrict__ maskp,
                    const float* __restrict__ b_qkv, const float* __restrict__ b_proj,
                    const short* __restrict__ wq, const short* __restrict__ wp,
                    float* __restrict__ out) {
  // LDS (16 KB):
  //  X [64 t][128 ch] bf16 @0, swz: cbyte ^ ((t&7)<<4); dead after ph1 reads
  //  O [64 t][128 ch] bf16 @0 aliases X, swz: chbyte ^ ((t&7)<<5)
  //  Q,K,V: registers only
  __shared__ __align__(16) char smem[16384];

  const int bw    = blockIdx.x;
  const int wv    = threadIdx.x >> 6;
  const int lane  = threadIdx.x & 63;
  const int g     = lane >> 4;
  const int j16   = lane & 15;
  const int wmask = bw & (NW - 1);

  // ---------------- Phase 0: stage x -> LDS bf16, swizzled ----------------
  {
    const int tid = threadIdx.x;
    const int t   = tid >> 2;            // 0..63
    const int c0  = (tid & 3) * 32;      // 32 consecutive channels per thread
    char* wb = smem + t * 256;
    const int swz = (t & 7) << 4;
    if (t < T49) {
      const float* p = x + (size_t)bw * (T49 * CDIM) + t * CDIM + c0;
#pragma unroll
      for (int q = 0; q < 4; ++q) {
        const float4 v0 = *(const float4*)(p + q * 8);
        const float4 v1 = *(const float4*)(p + q * 8 + 4);
        uint4 u;
        u.x = pk2(v0.x, v0.y); u.y = pk2(v0.z, v0.w);
        u.z = pk2(v1.x, v1.y); u.w = pk2(v1.z, v1.w);
        *(uint4*)(wb + ((c0 * 2 + q * 16) ^ swz)) = u;
      }
    } else {
#pragma unroll
      for (int q = 0; q < 4; ++q)
        *(uint4*)(wb + ((c0 * 2 + q * 16) ^ swz)) = make_uint4(0u, 0u, 0u, 0u);
    }
  }
  __syncthreads();

  // x fragment from LDS: serves as A (natural, m=t) AND B (swapped, n=t)
  auto XF = [&](int tt, int kt) -> bf16x8 {
    const int t = tt * 16 + j16;
    return *(const bf16x8*)(smem + t * 256 + ((kt * 64 + g * 16) ^ ((t & 7) << 4)));
  };

  // ---------------- Phase 1: QKV -> registers (wave wv = head wv) ----------------
  unsigned int pkQ[2][4][2];  // [d-tile][tt][pair]: pairs along channel (swapped D[c][t])
  unsigned int pkK[2][4][2];  // same layout
  unsigned int pkV[2][4][2];  // pairs along token (natural D[t][c])

#pragma unroll
  for (int ni = 0; ni < 6; ++ni) {
    const int ct = (ni < 2) ? (wv * 2 + ni)
                 : (ni < 4) ? (8 + wv * 2 + (ni - 2))
                            : (16 + wv * 2 + (ni - 4));
    bf16x8 wf[4];                                     // w frag: row c=ct*16+j16, k=kt*32+g*8..+7
#pragma unroll
    for (int kt = 0; kt < 4; ++kt)
      wf[kt] = *(const bf16x8*)(wq + (ct * 16 + j16) * CDIM + kt * 32 + g * 8);

    if (ni < 4) {
      // swapped: D[c][t]; lane holds channels c0..c0+3 at token t
      const int   c0 = ct * 16 + g * 4;
      float4 b4 = *(const float4*)(b_qkv + c0);
      if (ni < 2) { b4.x *= SCALEF; b4.y *= SCALEF; b4.z *= SCALEF; b4.w *= SCALEF; }
      const f32x4 cin = {b4.x, b4.y, b4.z, b4.w};    // bias as C-operand
#pragma unroll
      for (int tt = 0; tt < 4; ++tt) {
        f32x4 acc = cin;
#pragma unroll
        for (int kt = 0; kt < 4; ++kt)
          acc = __builtin_amdgcn_mfma_f32_16x16x32_bf16(wf[kt], XF(tt, kt), acc, 0, 0, 0);
        unsigned int p0 = pk2(acc[0], acc[1]);
        unsigned int p1 = pk2(acc[2], acc[3]);
        if (ni == 0)      { pkQ[0][tt][0] = p0; pkQ[0][tt][1] = p1; }
        else if (ni == 1) { pkQ[1][tt][0] = p0; pkQ[1][tt][1] = p1; }
        else if (ni == 2) { pkK[0][tt][0] = p0; pkK[0][tt][1] = p1; }
        else              { pkK[1][tt][0] = p0; pkK[1][tt][1] = p1; }
      }
    } else {
      // V natural: D[t][c]; bias constant across rows -> C-operand splat
      const int   vi   = ni - 4;
      const float bias = b_qkv[ct * 16 + j16];
      const f32x4 cin = {bias, bias, bias, bias};
#pragma unroll
      for (int tt = 0; tt < 4; ++tt) {
        f32x4 acc = cin;
#pragma unroll
        for (int kt = 0; kt < 4; ++kt)
          acc = __builtin_amdgcn_mfma_f32_16x16x32_bf16(XF(tt, kt), wf[kt], acc, 0, 0, 0);
        pkV[vi][tt][0] = pk2(acc[0], acc[1]);
        pkV[vi][tt][1] = pk2(acc[2], acc[3]);
      }
    }
  }

  // ---------------- Prologue: qb/kb/va via register redistribution ----------------
  // frag[mt] elem e = M[t=mt*16+j16][d=g*8+e]; source pk*[g>>1][mt][(e&3)>>1] at
  // lane ((2g+(e>>2))&3)*16+j16  (verified pattern, v5).
  const int gh   = g >> 1;
  const int srcA = (((2 * g    ) & 3) << 4) | j16;
  const int srcB = (((2 * g + 1) & 3) << 4) | j16;

  bf16x8 qb[4], kb[4];
#pragma unroll
  for (int mt = 0; mt < 4; ++mt) {
    {
      const unsigned int a0 = (unsigned)__shfl((int)pkQ[0][mt][0], srcA, 64);
      const unsigned int a1 = (unsigned)__shfl((int)pkQ[0][mt][1], srcA, 64);
      const unsigned int c0 = (unsigned)__shfl((int)pkQ[1][mt][0], srcA, 64);
      const unsigned int c1 = (unsigned)__shfl((int)pkQ[1][mt][1], srcA, 64);
      const unsigned int b0 = (unsigned)__shfl((int)pkQ[0][mt][0], srcB, 64);
      const unsigned int b1 = (unsigned)__shfl((int)pkQ[0][mt][1], srcB, 64);
      const unsigned int d0 = (unsigned)__shfl((int)pkQ[1][mt][0], srcB, 64);
      const unsigned int d1 = (unsigned)__shfl((int)pkQ[1][mt][1], srcB, 64);
      B8 u;
      u.u[0] = gh ? c0 : a0;
      u.u[1] = gh ? c1 : a1;
      u.u[2] = gh ? d0 : b0;
      u.u[3] = gh ? d1 : b1;
      qb[mt] = u.v;
    }
    {
      const unsigned int a0 = (unsigned)__shfl((int)pkK[0][mt][0], srcA, 64);
      const unsigned int a1 = (unsigned)__shfl((int)pkK[0][mt][1], srcA, 64);
      const unsigned int c0 = (unsigned)__shfl((int)pkK[1][mt][0], srcA, 64);
      const unsigned int c1 = (unsigned)__shfl((int)pkK[1][mt][1], srcA, 64);
      const unsigned int b0 = (unsigned)__shfl((int)pkK[0][mt][0], srcB, 64);
      const unsigned int b1 = (unsigned)__shfl((int)pkK[0][mt][1], srcB, 64);
      const unsigned int d0 = (unsigned)__shfl((int)pkK[1][mt][0], srcB, 64);
      const unsigned int d1 = (unsigned)__shfl((int)pkK[1][mt][1], srcB, 64);
      B8 u;
      u.u[0] = gh ? c0 : a0;
      u.u[1] = gh ? c1 : a1;
      u.u[2] = gh ? d0 : b0;
      u.u[3] = gh ? d1 : b1;
      kb[mt] = u.v;
    }
  }

  // va[dt][ks] elem e wants V[key=ks*32+8g+e][d=dt*16+j16]: source tile
  // tt = 2ks + (g>>1), lane (2g+(e>>2))&3 group, pair (e&3)>>1.
  bf16x8 va[2][2];
#pragma unroll
  for (int dt = 0; dt < 2; ++dt)
#pragma unroll
    for (int ks = 0; ks < 2; ++ks) {
      const unsigned int a0  = (unsigned)__shfl((int)pkV[dt][2 * ks    ][0], srcA, 64);
      const unsigned int a0h = (unsigned)__shfl((int)pkV[dt][2 * ks + 1][0], srcA, 64);
      const unsigned int a1  = (unsigned)__shfl((int)pkV[dt][2 * ks    ][1], srcA, 64);
      const unsigned int a1h = (unsigned)__shfl((int)pkV[dt][2 * ks + 1][1], srcA, 64);
      const unsigned int b0  = (unsigned)__shfl((int)pkV[dt][2 * ks    ][0], srcB, 64);
      const unsigned int b0h = (unsigned)__shfl((int)pkV[dt][2 * ks + 1][0], srcB, 64);
      const unsigned int b1  = (unsigned)__shfl((int)pkV[dt][2 * ks    ][1], srcB, 64);
      const unsigned int b1h = (unsigned)__shfl((int)pkV[dt][2 * ks + 1][1], srcB, 64);
      B8 u;
      u.u[0] = gh ? a0h : a0;
      u.u[1] = gh ? a1h : a1;
      u.u[2] = gh ? b0h : b0;
      u.u[3] = gh ? b1h : b1;
      va[dt][ks] = u.v;
    }

  __syncthreads();   // all X reads done -> O may overwrite X region

  // ---------------- Phases 2+3 merged, per q-tile nt (wave = head) ----------------
  char*        Ob  = smem;
  const float* mwb = maskp + wmask * 4096;

#pragma unroll
  for (int nt = 0; nt < 4; ++nt) {
    const float* mp = mwb + (nt * 16 + j16) * 64 + g * 4;
    float v[4][4];
#pragma unroll
    for (int mt = 0; mt < 4; ++mt) {
      const float4 m4 = *(const float4*)(mp + mt * 16);
      const f32x4 cin = {m4.x, m4.y, m4.z, m4.w};    // mask as C-operand
      const f32x4 s = __builtin_amdgcn_mfma_f32_16x16x32_bf16(kb[mt], qb[nt], cin, 0, 0, 0);
      // mask pre-shifted by row max in prep: exp directly, no max pass
      v[mt][0] = __expf(s[0]); v[mt][1] = __expf(s[1]);
      v[mt][2] = __expf(s[2]); v[mt][3] = __expf(s[3]);
    }
    // denominator chain (overlaps P-redistribute + PV below)
    float sr[8];
#pragma unroll
    for (int mt = 0; mt < 4; ++mt) {
      sr[2 * mt]     = v[mt][0] + v[mt][1];
      sr[2 * mt + 1] = v[mt][2] + v[mt][3];
    }
    float sum = ((sr[0] + sr[1]) + (sr[2] + sr[3])) + ((sr[4] + sr[5]) + (sr[6] + sr[7]));
    sum += __shfl_xor(sum, 16, 64);
    sum += __shfl_xor(sum, 32, 64);
    const float inv = 1.0f / sum;

    // P^T raw (unnormalized): pairs along key, 8 regs
    unsigned int pkn[4][2];
#pragma unroll
    for (int mt = 0; mt < 4; ++mt) {
      pkn[mt][0] = pk2(v[mt][0], v[mt][1]);
      pkn[mt][1] = pk2(v[mt][2], v[mt][3]);
    }

    // redistribute P^T + PV MFMAs
    f32x4 oacc[2] = {{0.f,0.f,0.f,0.f},{0.f,0.f,0.f,0.f}};
#pragma unroll
    for (int ks = 0; ks < 2; ++ks) {
      const unsigned int p00 = (unsigned)__shfl((int)pkn[2*ks  ][0], srcA, 64);
      const unsigned int p10 = (unsigned)__shfl((int)pkn[2*ks+1][0], srcA, 64);
      const unsigned int p01 = (unsigned)__shfl((int)pkn[2*ks  ][1], srcA, 64);
      const unsigned int p11 = (unsigned)__shfl((int)pkn[2*ks+1][1], srcA, 64);
      const unsigned int q00 = (unsigned)__shfl((int)pkn[2*ks  ][0], srcB, 64);
      const unsigned int q10 = (unsigned)__shfl((int)pkn[2*ks+1][0], srcB, 64);
      const unsigned int q01 = (unsigned)__shfl((int)pkn[2*ks  ][1], srcB, 64);
      const unsigned int q11 = (unsigned)__shfl((int)pkn[2*ks+1][1], srcB, 64);
      B8 bf;
      bf.u[0] = gh ? p10 : p00;
      bf.u[1] = gh ? p11 : p01;
      bf.u[2] = gh ? q10 : q00;
      bf.u[3] = gh ? q11 : q01;
#pragma unroll
      for (int dt = 0; dt < 2; ++dt)
        oacc[dt] = __builtin_amdgcn_mfma_f32_16x16x32_bf16(va[dt][ks], bf.v, oacc[dt], 0, 0, 0);
    }

    // deferred normalization: O = inv * (P_raw . V); lane's j16 == q on both sides
    const int to = nt * 16 + j16;
    const int sw = (to & 7) << 5;
#pragma unroll
    for (int dt = 0; dt < 2; ++dt) {
      const int ch0 = wv * 32 + dt * 16 + g * 4;
      const uint2 w2 = make_uint2(pk2(oacc[dt][0] * inv, oacc[dt][1] * inv),
                                  pk2(oacc[dt][2] * inv, oacc[dt][3] * inv));
      *(uint2*)(Ob + to * 256 + ((ch0 * 2) ^ sw)) = w2;
    }
  }
  __syncthreads();

  // ---------------- Phase 4: out = O @ wp^T + b ----------------
  {
    const char* Ob2 = smem;
    bf16x8 oa[4][4];
#pragma unroll
    for (int mt = 0; mt < 4; ++mt) {
      const int t = mt * 16 + j16;
      const int sw = (t & 7) << 5;
#pragma unroll
      for (int kt = 0; kt < 4; ++kt)
        oa[mt][kt] = *(const bf16x8*)(Ob2 + t * 256 + ((kt * 64 + g * 16) ^ sw));
    }
    float* ob = out + (size_t)bw * (T49 * CDIM);
#pragma unroll
    for (int ntl = 0; ntl < 2; ++ntl) {
      const int c = (wv * 2 + ntl) * 16 + j16;
      bf16x8 bfr[4];
#pragma unroll
      for (int kt = 0; kt < 4; ++kt)
        bfr[kt] = *(const bf16x8*)(wp + c * CDIM + kt * 32 + g * 8);
      const float bias = b_proj[c];
#pragma unroll
      for (int mt = 0; mt < 4; ++mt) {
        f32x4 acc = {0.f, 0.f, 0.f, 0.f};
#pragma unroll
        for (int kt = 0; kt < 4; ++kt)
          acc = __builtin_amdgcn_mfma_f32_16x16x32_bf16(oa[mt][kt], bfr[kt], acc, 0, 0, 0);
#pragma unroll
        for (int r = 0; r < 4; ++r) {
          const int t = mt * 16 + g * 4 + r;
          if (t < T49) ob[t * CDIM + c] = acc[r] + bias;
        }
      }
    }
  }
}

extern "C" void kernel_launch(void* const* d_in, const int* in_sizes, int n_in,
                              void* d_out, int out_size, void* d_ws, size_t ws_size,
                              hipStream_t stream) {
  const float* x      = (const float*)d_in[0];
  const float* mask   = (const float*)d_in[1];
  const float* w_qkv  = (const float*)d_in[2];
  const float* b_qkv  = (const float*)d_in[3];
  const float* w_proj = (const float*)d_in[4];
  const float* b_proj = (const float*)d_in[5];
  float* out = (float*)d_out;

  float* maskp = (float*)d_ws;                       // 64*64*64 f32 = 1 MB
  short* wq_bf = (short*)((char*)d_ws + 64*64*64*4); // 96 KB
  short* wp_bf = wq_bf + 3 * CDIM * CDIM;            // 32 KB

  hipLaunchKernelGGL(prep_kernel, dim3(1024), dim3(256), 0, stream,
                     w_qkv, w_proj, mask, wq_bf, wp_bf, maskp);
  hipLaunchKernelGGL(winattn_kernel, dim3(8192), dim3(256), 0, stream,
                     x, maskp, b_qkv, b_proj, wq_bf, wp_bf, out);
}

// Round 8
// 235.946 us; speedup vs baseline: 3.6394x; 3.6394x over previous
//
#include <hip/hip_runtime.h>
#include <hip/hip_bf16.h>

// WindowAttention fused kernel v11 (MI355X / gfx950)
// One block = one window. 4 waves, wave = head everywhere.
// v11 = v10 minus its two spill drivers, on the v7 champion structure:
//  - cooperative x staging (phase 0): block stages x->LDS bf16 ONCE; v7 had
//    every wave loading+converting the full 49x128 window (4x redundant).
//  - X/O alias @0 (16KB) + Q @16K -> 32KB, launch_bounds(256,4). NO
//    waves_per_eu squeeze (v10 lesson: ~102-reg budget -> 3.5GB scratch).
//  - Q -> LDS as in v7 (no pkQ; persistent packed arrays capped at 32 regs:
//    pkK+pkV only). kb/va built by verified 8-shuffle redistribution.
//  - keeps v10's validated folds: mask as QK^T C-operand, bias as C-operand,
//    Q weights pre-scaled in prep, pre-shifted mask (no max pass),
//    deferred normalization, merged ph2+3.

#define T49  49
#define CDIM 128
#define NW   64
#define SCALEF 0.17677669529663689f   // 1/sqrt(32)

typedef short bf16x8 __attribute__((ext_vector_type(8)));
typedef float f32x4  __attribute__((ext_vector_type(4)));

union B8 { unsigned int u[4]; bf16x8 v; };

__device__ __forceinline__ unsigned int pk2(float a, float b) {
  __hip_bfloat162 h = __float22bfloat162_rn(make_float2(a, b));
  unsigned int u;
  __builtin_memcpy(&u, &h, 4);
  return u;
}

__device__ __forceinline__ unsigned short f2bf(float f) {
  unsigned int u = __builtin_bit_cast(unsigned int, f);
  u += 0x7fffu + ((u >> 16) & 1u);
  return (unsigned short)(u >> 16);
}

// prep: bf16 weights (Q rows pre-scaled by SCALEF) + padded mask
//   maskp[w][q][k] = mask - rowmax(mask)  (q<49,k<49)
//                  = -1e30                (q<49,k>=49)  -> exp()=0 exactly
//                  = 0                    (q>=49)       -> finite garbage, unused
__global__ void prep_kernel(const float* __restrict__ wq, const float* __restrict__ wp,
                            const float* __restrict__ mask,
                            short* __restrict__ wq_bf, short* __restrict__ wp_bf,
                            float* __restrict__ maskp) {
  const int i = blockIdx.x * 256 + threadIdx.x;      // grid covers 262144
  const int w = i >> 12, q = (i >> 6) & 63, k = i & 63;
  // one wave == one (w,q) row, lane == k  (256 % 64 == 0)
  float val = -3.0e38f;
  if (q < T49 && k < T49) val = mask[(w * T49 + q) * T49 + k];
  float rm = val;
  rm = fmaxf(rm, __shfl_xor(rm, 1, 64));
  rm = fmaxf(rm, __shfl_xor(rm, 2, 64));
  rm = fmaxf(rm, __shfl_xor(rm, 4, 64));
  rm = fmaxf(rm, __shfl_xor(rm, 8, 64));
  rm = fmaxf(rm, __shfl_xor(rm, 16, 64));
  rm = fmaxf(rm, __shfl_xor(rm, 32, 64));
  float mv;
  if (q >= T49)      mv = 0.0f;
  else if (k >= T49) mv = -1e30f;
  else               mv = val - rm;
  maskp[i] = mv;
  if (i < 3 * CDIM * CDIM) {
    float wv_ = wq[i];
    if (i < CDIM * CDIM) wv_ *= SCALEF;              // Q rows pre-scaled
    wq_bf[i] = (short)f2bf(wv_);
  }
  if (i < CDIM * CDIM) wp_bf[i] = (short)f2bf(wp[i]);
}

__global__ __launch_bounds__(256, 4)
void winattn_kernel(const float* __restrict__ x, const float* __restrict__ maskp,
                    const float* __restrict__ b_qkv, const float* __restrict__ b_proj,
                    const short* __restrict__ wq, const short* __restrict__ wp,
                    float* __restrict__ out) {
  // LDS (32 KB):
  //  X [64 t][128 ch] bf16 @0,     swz: cbyte ^ ((t&7)<<4); dead after ph1 reads
  //  O [64 t][128 ch] bf16 @0 aliases X, swz: chbyte ^ ((t&7)<<5)
  //  Q [4h][64 t][32 d] bf16 @16384, swz: dbyte ^ ((t&3)<<4)
  //  K,V: registers only (pkK, pkV)
  __shared__ __align__(16) char smem[32768];
  constexpr int XO_BASE = 0, Q_BASE = 16384;

  const int bw    = blockIdx.x;
  const int wv    = threadIdx.x >> 6;
  const int lane  = threadIdx.x & 63;
  const int g     = lane >> 4;
  const int j16   = lane & 15;
  const int wmask = bw & (NW - 1);

  // ---------------- Phase 0: stage x -> LDS bf16, swizzled (ONCE per block) ----------------
  {
    const int tid = threadIdx.x;
    const int t   = tid >> 2;            // 0..63
    const int c0  = (tid & 3) * 32;      // 32 consecutive channels per thread
    char* wb = smem + XO_BASE + t * 256;
    const int swz = (t & 7) << 4;
    if (t < T49) {
      const float* p = x + (size_t)bw * (T49 * CDIM) + t * CDIM + c0;
#pragma unroll
      for (int q = 0; q < 4; ++q) {
        const float4 v0 = *(const float4*)(p + q * 8);
        const float4 v1 = *(const float4*)(p + q * 8 + 4);
        uint4 u;
        u.x = pk2(v0.x, v0.y); u.y = pk2(v0.z, v0.w);
        u.z = pk2(v1.x, v1.y); u.w = pk2(v1.z, v1.w);
        *(uint4*)(wb + ((c0 * 2 + q * 16) ^ swz)) = u;
      }
    } else {
#pragma unroll
      for (int q = 0; q < 4; ++q)
        *(uint4*)(wb + ((c0 * 2 + q * 16) ^ swz)) = make_uint4(0u, 0u, 0u, 0u);
    }
  }
  __syncthreads();

  // x fragment from LDS: serves as A (natural, m=t) AND B (swapped, n=t)
  auto XF = [&](int tt, int kt) -> bf16x8 {
    const int t = tt * 16 + j16;
    return *(const bf16x8*)(smem + XO_BASE + t * 256 +
                            ((kt * 64 + g * 16) ^ ((t & 7) << 4)));
  };

  // ---------------- Phase 1: QKV (wave wv = head wv) ----------------
  unsigned int pkK[2][4][2];  // [d-tile][tt][pair]: pairs along channel (swapped D[c][t])
  unsigned int pkV[2][4][2];  // pairs along token (natural D[t][c])

#pragma unroll
  for (int ni = 0; ni < 6; ++ni) {
    const int ct = (ni < 2) ? (wv * 2 + ni)
                 : (ni < 4) ? (8 + wv * 2 + (ni - 2))
                            : (16 + wv * 2 + (ni - 4));
    bf16x8 wf[4];                                     // w frag: row c=ct*16+j16, k=kt*32+g*8..+7
#pragma unroll
    for (int kt = 0; kt < 4; ++kt)
      wf[kt] = *(const bf16x8*)(wq + (ct * 16 + j16) * CDIM + kt * 32 + g * 8);

    if (ni < 4) {
      // swapped: D[c][t]; lane holds channels c0..c0+3 at token t
      const int   c0 = ct * 16 + g * 4;
      float4 b4 = *(const float4*)(b_qkv + c0);
      if (ni < 2) { b4.x *= SCALEF; b4.y *= SCALEF; b4.z *= SCALEF; b4.w *= SCALEF; }
      const f32x4 cin = {b4.x, b4.y, b4.z, b4.w};    // bias as C-operand
      if (ni < 2) {
        // Q -> LDS (read back by same wave in prologue; v7 store pattern)
        char* base = smem + Q_BASE + wv * 4096;
        const int d0 = c0 & 31;
#pragma unroll
        for (int tt = 0; tt < 4; ++tt) {
          f32x4 acc = cin;
#pragma unroll
          for (int kt = 0; kt < 4; ++kt)
            acc = __builtin_amdgcn_mfma_f32_16x16x32_bf16(wf[kt], XF(tt, kt), acc, 0, 0, 0);
          const int t = tt * 16 + j16;
          const uint2 w2 = make_uint2(pk2(acc[0], acc[1]), pk2(acc[2], acc[3]));
          *(uint2*)(base + t * 64 + ((d0 * 2) ^ ((t & 3) << 4))) = w2;
        }
      } else {
        // K -> registers
        const int vi = ni - 2;
#pragma unroll
        for (int tt = 0; tt < 4; ++tt) {
          f32x4 acc = cin;
#pragma unroll
          for (int kt = 0; kt < 4; ++kt)
            acc = __builtin_amdgcn_mfma_f32_16x16x32_bf16(wf[kt], XF(tt, kt), acc, 0, 0, 0);
          pkK[vi][tt][0] = pk2(acc[0], acc[1]);
          pkK[vi][tt][1] = pk2(acc[2], acc[3]);
        }
      }
    } else {
      // V natural: D[t][c]; bias constant across rows -> C-operand splat
      const int   vi   = ni - 4;
      const float bias = b_qkv[ct * 16 + j16];
      const f32x4 cin = {bias, bias, bias, bias};
#pragma unroll
      for (int tt = 0; tt < 4; ++tt) {
        f32x4 acc = cin;
#pragma unroll
        for (int kt = 0; kt < 4; ++kt)
          acc = __builtin_amdgcn_mfma_f32_16x16x32_bf16(XF(tt, kt), wf[kt], acc, 0, 0, 0);
        pkV[vi][tt][0] = pk2(acc[0], acc[1]);
        pkV[vi][tt][1] = pk2(acc[2], acc[3]);
      }
    }
  }
  // NO barrier: qb reads this wave's own Q writes; kb from own regs.

  // ---------------- Prologue: qb from LDS; kb from pkK; va from pkV ----------------
  const int gh   = g >> 1;
  const int srcA = (((2 * g    ) & 3) << 4) | j16;
  const int srcB = (((2 * g + 1) & 3) << 4) | j16;

  const char* Qb = smem + Q_BASE + wv * 4096;
  bf16x8 qb[4];
#pragma unroll
  for (int mt = 0; mt < 4; ++mt) {
    const int t = mt * 16 + j16;
    qb[mt] = *(const bf16x8*)(Qb + t * 64 + ((g * 16) ^ ((t & 3) << 4)));
  }

  // kb[mt] elem e = K[t=mt*16+j16][d=g*8+e]; source pkK[g>>1][mt][(e&3)>>1] at
  // lane ((2g+(e>>2))&3)*16+j16  (verified pattern).
  bf16x8 kb[4];
#pragma unroll
  for (int mt = 0; mt < 4; ++mt) {
    const unsigned int a0 = (unsigned)__shfl((int)pkK[0][mt][0], srcA, 64);
    const unsigned int a1 = (unsigned)__shfl((int)pkK[0][mt][1], srcA, 64);
    const unsigned int c0 = (unsigned)__shfl((int)pkK[1][mt][0], srcA, 64);
    const unsigned int c1 = (unsigned)__shfl((int)pkK[1][mt][1], srcA, 64);
    const unsigned int b0 = (unsigned)__shfl((int)pkK[0][mt][0], srcB, 64);
    const unsigned int b1 = (unsigned)__shfl((int)pkK[0][mt][1], srcB, 64);
    const unsigned int d0 = (unsigned)__shfl((int)pkK[1][mt][0], srcB, 64);
    const unsigned int d1 = (unsigned)__shfl((int)pkK[1][mt][1], srcB, 64);
    B8 u;
    u.u[0] = gh ? c0 : a0;
    u.u[1] = gh ? c1 : a1;
    u.u[2] = gh ? d0 : b0;
    u.u[3] = gh ? d1 : b1;
    kb[mt] = u.v;
  }

  // va[dt][ks] elem e wants V[key=ks*32+8g+e][d=dt*16+j16]: source tile
  // tt = 2ks + (g>>1), lane (2g+(e>>2))&3 group, pair (e&3)>>1.
  bf16x8 va[2][2];
#pragma unroll
  for (int dt = 0; dt < 2; ++dt)
#pragma unroll
    for (int ks = 0; ks < 2; ++ks) {
      const unsigned int a0  = (unsigned)__shfl((int)pkV[dt][2 * ks    ][0], srcA, 64);
      const unsigned int a0h = (unsigned)__shfl((int)pkV[dt][2 * ks + 1][0], srcA, 64);
      const unsigned int a1  = (unsigned)__shfl((int)pkV[dt][2 * ks    ][1], srcA, 64);
      const unsigned int a1h = (unsigned)__shfl((int)pkV[dt][2 * ks + 1][1], srcA, 64);
      const unsigned int b0  = (unsigned)__shfl((int)pkV[dt][2 * ks    ][0], srcB, 64);
      const unsigned int b0h = (unsigned)__shfl((int)pkV[dt][2 * ks + 1][0], srcB, 64);
      const unsigned int b1  = (unsigned)__shfl((int)pkV[dt][2 * ks    ][1], srcB, 64);
      const unsigned int b1h = (unsigned)__shfl((int)pkV[dt][2 * ks + 1][1], srcB, 64);
      B8 u;
      u.u[0] = gh ? a0h : a0;
      u.u[1] = gh ? a1h : a1;
      u.u[2] = gh ? b0h : b0;
      u.u[3] = gh ? b1h : b1;
      va[dt][ks] = u.v;
    }

  __syncthreads();   // all X reads (ph1) + own Q reads done -> O may overwrite X

  // ---------------- Phases 2+3 merged, per q-tile nt (wave = head) ----------------
  char*        Ob  = smem + XO_BASE;
  const float* mwb = maskp + wmask * 4096;

#pragma unroll
  for (int nt = 0; nt < 4; ++nt) {
    const float* mp = mwb + (nt * 16 + j16) * 64 + g * 4;
    float v[4][4];
#pragma unroll
    for (int mt = 0; mt < 4; ++mt) {
      const float4 m4 = *(const float4*)(mp + mt * 16);
      const f32x4 cin = {m4.x, m4.y, m4.z, m4.w};    // mask as C-operand
      const f32x4 s = __builtin_amdgcn_mfma_f32_16x16x32_bf16(kb[mt], qb[nt], cin, 0, 0, 0);
      // mask pre-shifted by row max in prep: exp directly, no max pass
      v[mt][0] = __expf(s[0]); v[mt][1] = __expf(s[1]);
      v[mt][2] = __expf(s[2]); v[mt][3] = __expf(s[3]);
    }
    // denominator chain (overlaps P-redistribute + PV below)
    float sr[8];
#pragma unroll
    for (int mt = 0; mt < 4; ++mt) {
      sr[2 * mt]     = v[mt][0] + v[mt][1];
      sr[2 * mt + 1] = v[mt][2] + v[mt][3];
    }
    float sum = ((sr[0] + sr[1]) + (sr[2] + sr[3])) + ((sr[4] + sr[5]) + (sr[6] + sr[7]));
    sum += __shfl_xor(sum, 16, 64);
    sum += __shfl_xor(sum, 32, 64);
    const float inv = 1.0f / sum;

    // P^T raw (unnormalized): pairs along key, 8 regs
    unsigned int pkn[4][2];
#pragma unroll
    for (int mt = 0; mt < 4; ++mt) {
      pkn[mt][0] = pk2(v[mt][0], v[mt][1]);
      pkn[mt][1] = pk2(v[mt][2], v[mt][3]);
    }

    // redistribute P^T + PV MFMAs
    f32x4 oacc[2] = {{0.f,0.f,0.f,0.f},{0.f,0.f,0.f,0.f}};
#pragma unroll
    for (int ks = 0; ks < 2; ++ks) {
      const unsigned int p00 = (unsigned)__shfl((int)pkn[2*ks  ][0], srcA, 64);
      const unsigned int p10 = (unsigned)__shfl((int)pkn[2*ks+1][0], srcA, 64);
      const unsigned int p01 = (unsigned)__shfl((int)pkn[2*ks  ][1], srcA, 64);
      const unsigned int p11 = (unsigned)__shfl((int)pkn[2*ks+1][1], srcA, 64);
      const unsigned int q00 = (unsigned)__shfl((int)pkn[2*ks  ][0], srcB, 64);
      const unsigned int q10 = (unsigned)__shfl((int)pkn[2*ks+1][0], srcB, 64);
      const unsigned int q01 = (unsigned)__shfl((int)pkn[2*ks  ][1], srcB, 64);
      const unsigned int q11 = (unsigned)__shfl((int)pkn[2*ks+1][1], srcB, 64);
      B8 bf;
      bf.u[0] = gh ? p10 : p00;
      bf.u[1] = gh ? p11 : p01;
      bf.u[2] = gh ? q10 : q00;
      bf.u[3] = gh ? q11 : q01;
#pragma unroll
      for (int dt = 0; dt < 2; ++dt)
        oacc[dt] = __builtin_amdgcn_mfma_f32_16x16x32_bf16(va[dt][ks], bf.v, oacc[dt], 0, 0, 0);
    }

    // deferred normalization: O = inv * (P_raw . V); lane's j16 == q on both sides
    const int to = nt * 16 + j16;
    const int sw = (to & 7) << 5;
#pragma unroll
    for (int dt = 0; dt < 2; ++dt) {
      const int ch0 = wv * 32 + dt * 16 + g * 4;
      const uint2 w2 = make_uint2(pk2(oacc[dt][0] * inv, oacc[dt][1] * inv),
                                  pk2(oacc[dt][2] * inv, oacc[dt][3] * inv));
      *(uint2*)(Ob + to * 256 + ((ch0 * 2) ^ sw)) = w2;
    }
  }
  __syncthreads();

  // ---------------- Phase 4: out = O @ wp^T + b ----------------
  {
    const char* Ob2 = smem + XO_BASE;
    bf16x8 oa[4][4];
#pragma unroll
    for (int mt = 0; mt < 4; ++mt) {
      const int t = mt * 16 + j16;
      const int sw = (t & 7) << 5;
#pragma unroll
      for (int kt = 0; kt < 4; ++kt)
        oa[mt][kt] = *(const bf16x8*)(Ob2 + t * 256 + ((kt * 64 + g * 16) ^ sw));
    }
    float* ob = out + (size_t)bw * (T49 * CDIM);
#pragma unroll
    for (int ntl = 0; ntl < 2; ++ntl) {
      const int c = (wv * 2 + ntl) * 16 + j16;
      bf16x8 bfr[4];
#pragma unroll
      for (int kt = 0; kt < 4; ++kt)
        bfr[kt] = *(const bf16x8*)(wp + c * CDIM + kt * 32 + g * 8);
      const float bias = b_proj[c];
#pragma unroll
      for (int mt = 0; mt < 4; ++mt) {
        f32x4 acc = {0.f, 0.f, 0.f, 0.f};
#pragma unroll
        for (int kt = 0; kt < 4; ++kt)
          acc = __builtin_amdgcn_mfma_f32_16x16x32_bf16(oa[mt][kt], bfr[kt], acc, 0, 0, 0);
#pragma unroll
        for (int r = 0; r < 4; ++r) {
          const int t = mt * 16 + g * 4 + r;
          if (t < T49) ob[t * CDIM + c] = acc[r] + bias;
        }
      }
    }
  }
}

extern "C" void kernel_launch(void* const* d_in, const int* in_sizes, int n_in,
                              void* d_out, int out_size, void* d_ws, size_t ws_size,
                              hipStream_t stream) {
  const float* x      = (const float*)d_in[0];
  const float* mask   = (const float*)d_in[1];
  const float* w_qkv  = (const float*)d_in[2];
  const float* b_qkv  = (const float*)d_in[3];
  const float* w_proj = (const float*)d_in[4];
  const float* b_proj = (const float*)d_in[5];
  float* out = (float*)d_out;

  float* maskp = (float*)d_ws;                       // 64*64*64 f32 = 1 MB
  short* wq_bf = (short*)((char*)d_ws + 64*64*64*4); // 96 KB
  short* wp_bf = wq_bf + 3 * CDIM * CDIM;            // 32 KB

  hipLaunchKernelGGL(prep_kernel, dim3(1024), dim3(256), 0, stream,
                     w_qkv, w_proj, mask, wq_bf, wp_bf, maskp);
  hipLaunchKernelGGL(winattn_kernel, dim3(8192), dim3(256), 0, stream,
                     x, maskp, b_qkv, b_proj, wq_bf, wp_bf, out);
}